// Round 12
// baseline (4823.103 us; speedup 1.0000x reference)
//
#include <hip/hip_runtime.h>
#include <hip/hip_bf16.h>

#define T_NUM_TABLES 26
#define T_NUM_ROWS 50000
#define T_WIDTH 128
#define T_BATCH 4096
#define T_NNZ 20
#define T_NUM_NUM 13
#define T_DE (T_NUM_TABLES * T_WIDTH) /* 3328 = 64*52 */

typedef __attribute__((ext_vector_type(4))) float f32x4;
typedef __attribute__((ext_vector_type(8))) short bf16x8;

// ---- fused dispatch layout: [0,512) gemm1 | [512,6432) prep | [6432,19744) pool
#define G1_BLKS 512
#define PREP_OFF G1_BLKS
#define PREP_JOBS (1664 + 128 + 32 + T_BATCH) /* 5920 */
#define POOL_OFF (PREP_OFF + PREP_JOBS)       /* 6432 */
#define POOL_JOBS (512 * T_NUM_TABLES)        /* 13312 */
#define TOTAL_BLKS (POOL_OFF + POOL_JOBS)     /* 19744 */
// flags (in d_ws[0..255]): [0..25] per-table pool counters (->512),
//                          [26] W1-transpose (->1664), [27] numbias (->4096)

__device__ __forceinline__ void wait_flag(unsigned int* f, unsigned int tgt) {
  while (__hip_atomic_load(f, __ATOMIC_RELAXED, __HIP_MEMORY_SCOPE_AGENT) < tgt)
    __builtin_amdgcn_s_sleep(8);
  __threadfence(); // acquire: invalidate stale L1/L2 lines before consuming produced data
}

__device__ __forceinline__ void mark_done(unsigned int* f) {
  __syncthreads(); // all block stores drained (vmcnt0 before barrier)
  if (threadIdx.x == 0)
    __hip_atomic_fetch_add(f, 1u, __ATOMIC_RELEASE, __HIP_MEMORY_SCOPE_AGENT);
}

// ================= depth-2 counted-vmcnt GEMM body (T3/T4/T5) =================
// 4 waves 2x2; per-wave (BM/2)x(BN/2); 16x16x32 frags.
// MODE 0: bf16 out. MODE 2: fused final dot -> atomicAdd out.
// SYNC: producer-consumer waits on per-table/prep flags (fused gemm1 only).
template <int BM, int BN, int RELU, int MODE, bool SYNC>
__device__ __forceinline__ void gemm_body(
    const __hip_bfloat16* __restrict__ A, const __hip_bfloat16* __restrict__ Bt,
    const float* __restrict__ bias1, const float* __restrict__ bias2d,
    const float* __restrict__ W4, __hip_bfloat16* __restrict__ Ch,
    float* __restrict__ outv, int M, int N, int Kp,
    int bx, int by, char* smem, unsigned int* flags) {
  constexpr int MR = BM / 32, NR = BN / 32;
  constexpr int BUFB = BM * 128 + BN * 128;
  constexpr int L = BM / 32 + BN / 32;
  const int tid = threadIdx.x;
  const int wave = tid >> 6, lane = tid & 63;
  const int m0 = bx * BM, n0 = by * BN;
  const int wr = wave >> 1, wc = wave & 1;
  f32x4 acc[MR][NR] = {};
  const size_t strideA = (size_t)Kp * 2;

  auto stage = [&](int kt, int buf) {
    const int k0 = kt << 6;
    char* As = smem + buf * BUFB;
    char* Bs = As + BM * 128;
#pragma unroll
    for (int it = 0; it < BM / 32; ++it) {
      int chunk = wave + it * 4;
      int p = chunk * 1024 + lane * 16;
      int row = p >> 7, colb = p & 127;
      int colb_g = colb ^ ((row & 7) << 4); // inverse-swizzle SOURCE
      size_t goff = (size_t)(m0 + row) * strideA + (size_t)k0 * 2 + colb_g;
      __builtin_amdgcn_global_load_lds(
          (const __attribute__((address_space(1))) void*)((const char*)A + goff),
          (__attribute__((address_space(3))) void*)(As + chunk * 1024), 16, 0, 0);
    }
#pragma unroll
    for (int it = 0; it < BN / 32; ++it) {
      int chunk = wave + it * 4;
      int p = chunk * 1024 + lane * 16;
      int row = p >> 7, colb = p & 127;
      int colb_g = colb ^ ((row & 7) << 4);
      size_t goff = (size_t)(n0 + row) * strideA + (size_t)k0 * 2 + colb_g;
      __builtin_amdgcn_global_load_lds(
          (const __attribute__((address_space(1))) void*)((const char*)Bt + goff),
          (__attribute__((address_space(3))) void*)(Bs + chunk * 1024), 16, 0, 0);
    }
  };

  const int nt = Kp >> 6;
  if (SYNC) {
    wait_flag(&flags[26], 1664); // w1t fully transposed
    wait_flag(&flags[0], 512);   // table 0 pooled (covers tiles 0 and 1)
  }
  stage(0, 0);
  if (nt > 1) stage(1, 1);
  int cur = 0;
  for (int t = 0; t < nt; ++t) {
    if (t + 1 < nt) {
      asm volatile("s_waitcnt vmcnt(%0)" ::"n"(L) : "memory");
    } else {
      asm volatile("s_waitcnt vmcnt(0)" ::: "memory");
    }
    __builtin_amdgcn_sched_barrier(0);
    __builtin_amdgcn_s_barrier();
    __builtin_amdgcn_sched_barrier(0);

    char* As = smem + cur * BUFB;
    char* Bs = As + BM * 128;
#pragma unroll
    for (int ks = 0; ks < 2; ++ks) {
      bf16x8 af[MR], bfr[NR];
      const int cb = (ks * 32 + ((lane >> 4) * 8)) * 2;
#pragma unroll
      for (int m = 0; m < MR; ++m) {
        int row = wr * (BM / 2) + m * 16 + (lane & 15);
        int addr = row * 128 + (cb ^ ((row & 7) << 4));
        af[m] = *(const bf16x8*)(As + addr);
      }
#pragma unroll
      for (int n = 0; n < NR; ++n) {
        int row = wc * (BN / 2) + n * 16 + (lane & 15);
        int addr = row * 128 + (cb ^ ((row & 7) << 4));
        bfr[n] = *(const bf16x8*)(Bs + addr);
      }
      __builtin_amdgcn_s_setprio(1);
#pragma unroll
      for (int m = 0; m < MR; ++m)
#pragma unroll
        for (int n = 0; n < NR; ++n)
          acc[m][n] = __builtin_amdgcn_mfma_f32_16x16x32_bf16(af[m], bfr[n], acc[m][n], 0, 0, 0);
      __builtin_amdgcn_s_setprio(0);
    }

    __builtin_amdgcn_sched_barrier(0);
    __builtin_amdgcn_s_barrier();
    __builtin_amdgcn_sched_barrier(0);
    if (t + 2 < nt) {
      if (SYNC) wait_flag(&flags[(t + 2) >> 1], 512); // table feeding tile t+2
      stage(t + 2, cur);
    }
    cur ^= 1;
  }

  if (SYNC) wait_flag(&flags[27], T_BATCH); // c0 ready for epilogue

  // epilogue: C/D layout col=lane&15, row=(lane>>4)*4+i
#pragma unroll
  for (int m = 0; m < MR; ++m) {
#pragma unroll
    for (int n = 0; n < NR; ++n) {
      int col = n0 + wc * (BN / 2) + n * 16 + (lane & 15);
      float bv = bias1 ? bias1[col] : 0.f;
      float w4c = (MODE == 2) ? W4[col] : 0.f;
      float dot[4];
#pragma unroll
      for (int i = 0; i < 4; ++i) {
        int row = m0 + wr * (BM / 2) + m * 16 + ((lane >> 4) * 4) + i;
        float v = acc[m][n][i] + bv;
        if (bias2d) v += bias2d[(size_t)row * N + col];
        if (RELU) v = fmaxf(v, 0.f);
        if (MODE == 0) {
          Ch[(size_t)row * N + col] = __float2bfloat16(v);
        } else {
          dot[i] = v * w4c;
        }
      }
      if (MODE == 2) {
#pragma unroll
        for (int i = 0; i < 4; ++i) {
#pragma unroll
          for (int mask = 1; mask < 16; mask <<= 1) dot[i] += __shfl_xor(dot[i], mask);
        }
        if ((lane & 15) == 0) {
          int rowb = m0 + wr * (BM / 2) + m * 16 + ((lane >> 4) * 4);
#pragma unroll
          for (int i = 0; i < 4; ++i) atomicAdd(&outv[rowb + i], dot[i]);
        }
      }
    }
  }
}

// ================= standalone GEMM kernel (layers 2,3) =================
template <int BM, int BN, int RELU, int MODE>
__global__ __launch_bounds__(256, 2) void gemm_k12(
    const __hip_bfloat16* __restrict__ A, const __hip_bfloat16* __restrict__ Bt,
    const float* __restrict__ bias1, const float* __restrict__ bias2d,
    const float* __restrict__ W4, __hip_bfloat16* __restrict__ Ch,
    float* __restrict__ outv, int M, int N, int Kp) {
  __shared__ char smem[2 * (BM * 128 + BN * 128)];
  gemm_body<BM, BN, RELU, MODE, false>(A, Bt, bias1, bias2d, W4, Ch, outv,
                                       M, N, Kp, blockIdx.x, blockIdx.y, smem, nullptr);
}

// ================= fused: gemm1 (sync-consumer) + prep + pool (producers) =================
__global__ __launch_bounds__(256, 4) void fused_v12(
    const float* __restrict__ tables, const int* __restrict__ cat,
    const float* __restrict__ W1, const float* __restrict__ W2,
    const float* __restrict__ W3, const float* __restrict__ b1,
    const float* __restrict__ b4, const float* __restrict__ num,
    __hip_bfloat16* __restrict__ xh, __hip_bfloat16* __restrict__ w1t,
    __hip_bfloat16* __restrict__ w2t, __hip_bfloat16* __restrict__ w3t,
    float* __restrict__ c0, float* __restrict__ a1, float* __restrict__ out,
    __hip_bfloat16* __restrict__ a1h, unsigned int* flags) {
  __shared__ char gsm[2 * (64 * 128 + 64 * 128)]; // 32KB gemm double-buffer
  __shared__ int sidx[8][T_NNZ];
  __shared__ float tile[32][33];
  __shared__ float snum[T_NUM_NUM];
  const int bid = blockIdx.x;

  if (bid < G1_BLKS) { // ---------------- gemm1 consumer: waits on table flags
    gemm_body<64, 64, 1, 0, true>(xh, w1t, nullptr, c0, nullptr, a1h, nullptr,
                                  T_BATCH, 512, T_DE, bid & 63, bid >> 6, gsm, flags);
    return;
  }

  if (bid < POOL_OFF) { // ---------------- prep producers
    int r = bid - PREP_OFF;
    if (r < 1664 + 128 + 32) { // weight transpose + bf16 cast
      const float* in;
      __hip_bfloat16* outt;
      int Kc, N, xb, yb;
      bool isW1 = (r < 1664);
      if (isW1)          { in = W1; outt = w1t; Kc = 3328; N = 512; xb = r % 104; yb = r / 104; }
      else if (r < 1792) { int q = r - 1664; in = W2; outt = w2t; Kc = 512; N = 256; xb = q % 16; yb = q / 16; }
      else               { int q = r - 1792; in = W3; outt = w3t; Kc = 256; N = 128; xb = q % 8;  yb = q / 8;  }
      int tx = threadIdx.x & 31, ty = threadIdx.x >> 5;
      int kb = xb * 32, nb = yb * 32;
      for (int rr = ty; rr < 32; rr += 8) tile[rr][tx] = in[(size_t)(kb + rr) * N + nb + tx];
      __syncthreads();
      for (int rr = ty; rr < 32; rr += 8)
        outt[(size_t)(nb + rr) * Kc + kb + tx] = __float2bfloat16(tile[tx][rr]);
      if (isW1) mark_done(&flags[26]);
      return;
    }
    { // numerical bias (exact fp32) + out init
      int b = r - 1824;
      if (threadIdx.x < T_NUM_NUM) snum[threadIdx.x] = num[b * T_NUM_NUM + threadIdx.x];
      if (threadIdx.x == 0) out[b] = b4[0];
      __syncthreads();
#pragma unroll
      for (int rep = 0; rep < 2; ++rep) {
        int n = threadIdx.x + rep * 256;
        float acc = b1[n];
#pragma unroll
        for (int j = 0; j < T_NUM_NUM; ++j)
          acc += snum[j] * W1[(size_t)(T_DE + j) * 512 + n];
        c0[(size_t)b * 512 + n] = acc;
      }
      mark_done(&flags[27]);
      return;
    }
  }

  { // ---------------- pool producer: float4 gathers, table-major
    int r = bid - POOL_OFF;
    const int t = r >> 9;
    const int g = r & 511;
    const int b0 = g * 8;
    const int tx = threadIdx.x & 31;
    const int ty = threadIdx.x >> 5;
    if (threadIdx.x < 8 * T_NNZ) {
      int y = threadIdx.x / T_NNZ, j = threadIdx.x % T_NNZ;
      sidx[y][j] = cat[((size_t)t * T_BATCH + b0 + y) * T_NNZ + j];
    }
    __syncthreads();
    const f32x4* tb = (const f32x4*)(tables + (size_t)t * T_NUM_ROWS * T_WIDTH);
    f32x4 acc = {0.f, 0.f, 0.f, 0.f};
#pragma unroll
    for (int j = 0; j < T_NNZ; ++j) acc += tb[(size_t)sidx[ty][j] * 32 + tx];
    ushort4 u;
    {
      __hip_bfloat16 h0 = __float2bfloat16(acc[0]), h1 = __float2bfloat16(acc[1]);
      __hip_bfloat16 h2 = __float2bfloat16(acc[2]), h3 = __float2bfloat16(acc[3]);
      u.x = *(unsigned short*)&h0; u.y = *(unsigned short*)&h1;
      u.z = *(unsigned short*)&h2; u.w = *(unsigned short*)&h3;
    }
    *(ushort4*)(&xh[(size_t)(b0 + ty) * T_DE + t * T_WIDTH + tx * 4]) = u;
    mark_done(&flags[t]);
  }
}

extern "C" void kernel_launch(void* const* d_in, const int* in_sizes, int n_in,
                              void* d_out, int out_size, void* d_ws, size_t ws_size,
                              hipStream_t stream) {
  const float* numerical = (const float*)d_in[0];
  const int* cat = (const int*)d_in[1];
  const float* tables = (const float*)d_in[2];
  const float* W1 = (const float*)d_in[3];
  const float* b1 = (const float*)d_in[4];
  const float* W2 = (const float*)d_in[5];
  const float* b2 = (const float*)d_in[6];
  const float* W3 = (const float*)d_in[7];
  const float* b3 = (const float*)d_in[8];
  const float* W4 = (const float*)d_in[9];
  const float* b4 = (const float*)d_in[10];
  float* out = (float*)d_out;

  unsigned int* flags = (unsigned int*)d_ws; // 28 counters in first 256 B
  char* ws = (char*)d_ws + 256;
  size_t off = 0;
  auto walloc = [&](size_t bytes) -> void* {
    void* p = ws + off;
    off = (off + bytes + 255) & ~(size_t)255;
    return p;
  };
  __hip_bfloat16* xh  = (__hip_bfloat16*)walloc((size_t)T_BATCH * T_DE * 2);
  __hip_bfloat16* w1t = (__hip_bfloat16*)walloc((size_t)512 * T_DE * 2);
  float*          c0  = (float*)walloc((size_t)T_BATCH * 512 * 4);
  __hip_bfloat16* a1  = (__hip_bfloat16*)walloc((size_t)T_BATCH * 512 * 2);
  __hip_bfloat16* w2t = (__hip_bfloat16*)walloc((size_t)256 * 512 * 2);
  __hip_bfloat16* a2  = (__hip_bfloat16*)walloc((size_t)T_BATCH * 256 * 2);
  __hip_bfloat16* w3t = (__hip_bfloat16*)walloc((size_t)128 * 256 * 2);

  hipMemsetAsync(flags, 0, 256, stream); // zero flags each call (graph-capture safe)

  fused_v12<<<TOTAL_BLKS, 256, 0, stream>>>(tables, cat, W1, W2, W3, b1, b4, numerical,
                                            xh, w1t, w2t, w3t, c0, nullptr, out, a1, flags);

  gemm_k12<64, 32, 1, 0><<<dim3(T_BATCH / 64, 256 / 32), 256, 0, stream>>>(
      a1, w2t, b2, nullptr, nullptr, a2, nullptr, T_BATCH, 256, 512);
  gemm_k12<32, 32, 1, 2><<<dim3(T_BATCH / 32, 128 / 32), 256, 0, stream>>>(
      a2, w3t, b3, nullptr, W4, nullptr, out, T_BATCH, 128, 256);
}

// Round 13
// 195.118 us; speedup vs baseline: 24.7189x; 24.7189x over previous
//
#include <hip/hip_runtime.h>
#include <hip/hip_bf16.h>

#define T_NUM_TABLES 26
#define T_NUM_ROWS 50000
#define T_WIDTH 128
#define T_BATCH 4096
#define T_NNZ 20
#define T_NUM_NUM 13
#define T_DE (T_NUM_TABLES * T_WIDTH) /* 3328 = 64*52 */

typedef __attribute__((ext_vector_type(4))) float f32x4;
typedef __attribute__((ext_vector_type(8))) short bf16x8;

// ================= fused pool + prep (no cross-block sync) =================
#define PJ_POOL (512 * T_NUM_TABLES)         /* 13312 */
#define PJ_WT (PJ_POOL + 1664 + 128 + 32)    /* 15136 */
#define PJ_TOTAL (PJ_WT + T_BATCH)           /* 19232 */

__global__ void poolprep_v13(const float* __restrict__ tables,
                             const int* __restrict__ cat,
                             const float* __restrict__ W1, const float* __restrict__ W2,
                             const float* __restrict__ W3, const float* __restrict__ b1,
                             const float* __restrict__ b4, const float* __restrict__ num,
                             __hip_bfloat16* __restrict__ xh,
                             __hip_bfloat16* __restrict__ w1t, __hip_bfloat16* __restrict__ w2t,
                             __hip_bfloat16* __restrict__ w3t, float* __restrict__ c0,
                             float* __restrict__ out) {
  __shared__ int sidx[8][T_NNZ];
  __shared__ float tile[32][33];
  __shared__ float snum[T_NUM_NUM];
  const int bid = blockIdx.x;

  if (bid < PJ_POOL) { // ---------------- pool: float4 gathers, table-major
    const int g = bid & 511;
    const int t = bid >> 9;
    const int b0 = g * 8;
    const int tx = threadIdx.x & 31;
    const int ty = threadIdx.x >> 5;
    if (threadIdx.x < 8 * T_NNZ) {
      int y = threadIdx.x / T_NNZ, j = threadIdx.x % T_NNZ;
      sidx[y][j] = cat[((size_t)t * T_BATCH + b0 + y) * T_NNZ + j];
    }
    __syncthreads();
    const f32x4* tb = (const f32x4*)(tables + (size_t)t * T_NUM_ROWS * T_WIDTH);
    f32x4 acc = {0.f, 0.f, 0.f, 0.f};
#pragma unroll
    for (int j = 0; j < T_NNZ; ++j) acc += tb[(size_t)sidx[ty][j] * 32 + tx];
    ushort4 u;
    {
      __hip_bfloat16 h0 = __float2bfloat16(acc[0]), h1 = __float2bfloat16(acc[1]);
      __hip_bfloat16 h2 = __float2bfloat16(acc[2]), h3 = __float2bfloat16(acc[3]);
      u.x = *(unsigned short*)&h0; u.y = *(unsigned short*)&h1;
      u.z = *(unsigned short*)&h2; u.w = *(unsigned short*)&h3;
    }
    *(ushort4*)(&xh[(size_t)(b0 + ty) * T_DE + t * T_WIDTH + tx * 4]) = u;
    return;
  }

  if (bid < PJ_WT) { // ---------------- weight transpose + bf16 cast
    int r = bid - PJ_POOL;
    const float* in;
    __hip_bfloat16* outt;
    int Kc, N, xb, yb;
    if (r < 1664)      { in = W1; outt = w1t; Kc = 3328; N = 512; xb = r % 104; yb = r / 104; }
    else if (r < 1792) { r -= 1664; in = W2; outt = w2t; Kc = 512; N = 256; xb = r % 16; yb = r / 16; }
    else               { r -= 1792; in = W3; outt = w3t; Kc = 256; N = 128; xb = r % 8;  yb = r / 8;  }
    int tx = threadIdx.x & 31, ty = threadIdx.x >> 5;
    int kb = xb * 32, nb = yb * 32;
    for (int rr = ty; rr < 32; rr += 8) tile[rr][tx] = in[(size_t)(kb + rr) * N + nb + tx];
    __syncthreads();
    for (int rr = ty; rr < 32; rr += 8)
      outt[(size_t)(nb + rr) * Kc + kb + tx] = __float2bfloat16(tile[tx][rr]);
    return;
  }

  { // ---------------- numerical bias (exact fp32) + out init
    int b = bid - PJ_WT;
    if (threadIdx.x < T_NUM_NUM) snum[threadIdx.x] = num[b * T_NUM_NUM + threadIdx.x];
    if (threadIdx.x == 0) out[b] = b4[0];
    __syncthreads();
#pragma unroll
    for (int rep = 0; rep < 2; ++rep) {
      int n = threadIdx.x + rep * 256;
      float acc = b1[n];
#pragma unroll
      for (int j = 0; j < T_NUM_NUM; ++j)
        acc += snum[j] * W1[(size_t)(T_DE + j) * 512 + n];
      c0[(size_t)b * 512 + n] = acc;
    }
  }
}

// ================= bf16 MFMA GEMM, depth-3 counted-vmcnt pipeline (T3/T4/T5) =================
template <int BM, int BN, int RELU, int MODE>
__global__ __launch_bounds__(256, 2) void gemm_v13(
    const __hip_bfloat16* __restrict__ A,   // [M][Kp]
    const __hip_bfloat16* __restrict__ Bt,  // [N][Kp]
    const float* __restrict__ bias1,        // [N] or null
    const float* __restrict__ bias2d,       // [M][N] or null
    const float* __restrict__ W4,           // MODE 2
    __hip_bfloat16* __restrict__ Ch,        // MODE 0
    float* __restrict__ outv,               // MODE 2
    int M, int N, int Kp) {
  constexpr int MR = BM / 32, NR = BN / 32;
  constexpr int BUFB = BM * 128 + BN * 128;
  constexpr int L = BM / 32 + BN / 32; // global_load_lds per wave per tile
  __shared__ char smem[3 * BUFB];

  const int tid = threadIdx.x;
  const int wave = tid >> 6;
  const int lane = tid & 63;
  const int m0 = blockIdx.x * BM;
  const int n0 = blockIdx.y * BN;
  const int wr = wave >> 1;
  const int wc = wave & 1;

  f32x4 acc[MR][NR] = {};
  const size_t strideA = (size_t)Kp * 2;

  auto stage = [&](int k0, int buf) {
    char* As = smem + buf * BUFB;
    char* Bs = As + BM * 128;
#pragma unroll
    for (int it = 0; it < BM / 32; ++it) {
      int chunk = wave + it * 4;
      int p = chunk * 1024 + lane * 16;
      int row = p >> 7, colb = p & 127;
      int colb_g = colb ^ ((row & 7) << 4); // inverse-swizzle SOURCE
      size_t goff = (size_t)(m0 + row) * strideA + (size_t)k0 * 2 + colb_g;
      __builtin_amdgcn_global_load_lds(
          (const __attribute__((address_space(1))) void*)((const char*)A + goff),
          (__attribute__((address_space(3))) void*)(As + chunk * 1024), 16, 0, 0);
    }
#pragma unroll
    for (int it = 0; it < BN / 32; ++it) {
      int chunk = wave + it * 4;
      int p = chunk * 1024 + lane * 16;
      int row = p >> 7, colb = p & 127;
      int colb_g = colb ^ ((row & 7) << 4);
      size_t goff = (size_t)(n0 + row) * strideA + (size_t)k0 * 2 + colb_g;
      __builtin_amdgcn_global_load_lds(
          (const __attribute__((address_space(1))) void*)((const char*)Bt + goff),
          (__attribute__((address_space(3))) void*)(Bs + chunk * 1024), 16, 0, 0);
    }
  };

  const int nt = Kp >> 6;
  stage(0, 0);
  if (nt > 1) stage(64, 1);
  if (nt > 2) stage(128, 2);
  int cur = 0;
  for (int t = 0; t < nt; ++t) {
    if (t + 2 < nt) {
      asm volatile("s_waitcnt vmcnt(%0)" ::"n"(2 * L) : "memory");
    } else if (t + 1 < nt) {
      asm volatile("s_waitcnt vmcnt(%0)" ::"n"(L) : "memory");
    } else {
      asm volatile("s_waitcnt vmcnt(0)" ::: "memory");
    }
    __builtin_amdgcn_sched_barrier(0);
    __builtin_amdgcn_s_barrier(); // buf[cur] ready for all waves
    __builtin_amdgcn_sched_barrier(0);

    char* As = smem + cur * BUFB;
    char* Bs = As + BM * 128;
#pragma unroll
    for (int ks = 0; ks < 2; ++ks) {
      bf16x8 af[MR], bfr[NR];
      const int cb = (ks * 32 + ((lane >> 4) * 8)) * 2;
#pragma unroll
      for (int m = 0; m < MR; ++m) {
        int row = wr * (BM / 2) + m * 16 + (lane & 15);
        int addr = row * 128 + (cb ^ ((row & 7) << 4));
        af[m] = *(const bf16x8*)(As + addr);
      }
#pragma unroll
      for (int n = 0; n < NR; ++n) {
        int row = wc * (BN / 2) + n * 16 + (lane & 15);
        int addr = row * 128 + (cb ^ ((row & 7) << 4));
        bfr[n] = *(const bf16x8*)(Bs + addr);
      }
      __builtin_amdgcn_s_setprio(1);
#pragma unroll
      for (int m = 0; m < MR; ++m)
#pragma unroll
        for (int n = 0; n < NR; ++n)
          acc[m][n] = __builtin_amdgcn_mfma_f32_16x16x32_bf16(af[m], bfr[n], acc[m][n], 0, 0, 0);
      __builtin_amdgcn_s_setprio(0);
    }

    __builtin_amdgcn_sched_barrier(0);
    __builtin_amdgcn_s_barrier(); // all waves done reading buf[cur]
    __builtin_amdgcn_sched_barrier(0);
    if (t + 3 < nt) stage((t + 3) << 6, cur); // refill the buffer just freed
    cur = (cur == 2) ? 0 : cur + 1;
  }

  // epilogue: C/D layout col=lane&15, row=(lane>>4)*4+i
#pragma unroll
  for (int m = 0; m < MR; ++m) {
#pragma unroll
    for (int n = 0; n < NR; ++n) {
      int col = n0 + wc * (BN / 2) + n * 16 + (lane & 15);
      float bv = bias1 ? bias1[col] : 0.f;
      float w4c = (MODE == 2) ? W4[col] : 0.f;
      float dot[4];
#pragma unroll
      for (int i = 0; i < 4; ++i) {
        int row = m0 + wr * (BM / 2) + m * 16 + ((lane >> 4) * 4) + i;
        float v = acc[m][n][i] + bv;
        if (bias2d) v += bias2d[(size_t)row * N + col];
        if (RELU) v = fmaxf(v, 0.f);
        if (MODE == 0) {
          Ch[(size_t)row * N + col] = __float2bfloat16(v);
        } else {
          dot[i] = v * w4c;
        }
      }
      if (MODE == 2) {
#pragma unroll
        for (int i = 0; i < 4; ++i) {
#pragma unroll
          for (int mask = 1; mask < 16; mask <<= 1) dot[i] += __shfl_xor(dot[i], mask);
        }
        if ((lane & 15) == 0) {
          int rowb = m0 + wr * (BM / 2) + m * 16 + ((lane >> 4) * 4);
#pragma unroll
          for (int i = 0; i < 4; ++i) atomicAdd(&outv[rowb + i], dot[i]);
        }
      }
    }
  }
}

extern "C" void kernel_launch(void* const* d_in, const int* in_sizes, int n_in,
                              void* d_out, int out_size, void* d_ws, size_t ws_size,
                              hipStream_t stream) {
  const float* numerical = (const float*)d_in[0];
  const int* cat = (const int*)d_in[1];
  const float* tables = (const float*)d_in[2];
  const float* W1 = (const float*)d_in[3];
  const float* b1 = (const float*)d_in[4];
  const float* W2 = (const float*)d_in[5];
  const float* b2 = (const float*)d_in[6];
  const float* W3 = (const float*)d_in[7];
  const float* b3 = (const float*)d_in[8];
  const float* W4 = (const float*)d_in[9];
  const float* b4 = (const float*)d_in[10];
  float* out = (float*)d_out;

  char* ws = (char*)d_ws;
  size_t off = 0;
  auto walloc = [&](size_t bytes) -> void* {
    void* p = ws + off;
    off = (off + bytes + 255) & ~(size_t)255;
    return p;
  };
  __hip_bfloat16* xh  = (__hip_bfloat16*)walloc((size_t)T_BATCH * T_DE * 2);
  __hip_bfloat16* w1t = (__hip_bfloat16*)walloc((size_t)512 * T_DE * 2);
  float*          c0  = (float*)walloc((size_t)T_BATCH * 512 * 4);
  __hip_bfloat16* a1  = (__hip_bfloat16*)walloc((size_t)T_BATCH * 512 * 2);
  __hip_bfloat16* w2t = (__hip_bfloat16*)walloc((size_t)256 * 512 * 2);
  __hip_bfloat16* a2  = (__hip_bfloat16*)walloc((size_t)T_BATCH * 256 * 2);
  __hip_bfloat16* w3t = (__hip_bfloat16*)walloc((size_t)128 * 256 * 2);

  poolprep_v13<<<PJ_TOTAL, 256, 0, stream>>>(tables, cat, W1, W2, W3, b1, b4, numerical,
                                             xh, w1t, w2t, w3t, c0, out);

  gemm_v13<64, 64, 1, 0><<<dim3(T_BATCH / 64, 512 / 64), 256, 0, stream>>>(
      xh, w1t, nullptr, c0, nullptr, a1, nullptr, T_BATCH, 512, T_DE);
  gemm_v13<64, 32, 1, 0><<<dim3(T_BATCH / 64, 256 / 32), 256, 0, stream>>>(
      a1, w2t, b2, nullptr, nullptr, a2, nullptr, T_BATCH, 256, 512);
  gemm_v13<32, 32, 1, 2><<<dim3(T_BATCH / 32, 128 / 32), 256, 0, stream>>>(
      a2, w3t, b3, nullptr, W4, nullptr, out, T_BATCH, 128, 256);
}